// Round 9
// baseline (462.434 us; speedup 1.0000x reference)
//
#include <hip/hip_runtime.h>
#include <math.h>

#define PRIME_Y 2654435761u

struct LevelParams { float scale; unsigned res; unsigned size; unsigned offset; };
struct EncParams { LevelParams lv[16]; };

typedef __attribute__((ext_vector_type(8))) short short8;
typedef __attribute__((ext_vector_type(4))) float f32x4;
typedef float v2f __attribute__((ext_vector_type(2)));

struct alignas(8) F2 { float x, y; };

// fp32 pair -> packed bf16 (RNE), low = a, high = b
__device__ inline unsigned bf2pack(float a, float b) {
  unsigned ua = __float_as_uint(a);
  unsigned ub = __float_as_uint(b);
  ua = (ua + 0x7FFFu + ((ua >> 16) & 1u)) >> 16;
  ub = (ub + 0x7FFFu + ((ub >> 16) & 1u)) & 0xFFFF0000u;
  return ua | ub;
}
__device__ inline v2f bfup(unsigned u) {
  v2f r;
  r.x = __uint_as_float(u << 16);
  r.y = __uint_as_float(u & 0xFFFF0000u);
  return r;
}
__device__ inline v2f bilerp(unsigned p00, unsigned p10, unsigned p01, unsigned p11,
                             float fx, float fy) {
  v2f t00 = bfup(p00), t10 = bfup(p10), t01 = bfup(p01), t11 = bfup(p11);
  float w0 = (1.0f - fx) * (1.0f - fy);
  float w1 = fx * (1.0f - fy);
  float w2 = (1.0f - fx) * fy;
  float w3 = fx * fy;
  return w0 * t00 + w1 * t10 + w2 * t01 + w3 * t11;
}

// table fp32 [n][2] -> packed bf16 [n]
__global__ __launch_bounds__(256) void cvt_table(const F2* __restrict__ in,
                                                 unsigned* __restrict__ outb,
                                                 int n) {
  int i = blockIdx.x * 256 + threadIdx.x;
  if (i < n) {
    F2 v = in[i];
    outb[i] = bf2pack(v.x, v.y);
  }
}

// LDS map (bytes):
//   [0,5120)     W0 bf16 [64][32] stride 80
//   [5120,7424)  W1 bf16 [16][64] stride 144 (rows 8..15 zero)
//   per-wave region (25600 B) at 7424 + w*25600:
//     [0,1024)        wc  fp32 [64 pts][4 corners]
//     [1024,5120)     guard (H_0 head)
//     [5120+5120s ..) F chunk s: 64 rows x 80 B  (row = c*16 + pt15)
//     H_s at [1024+5120s, 1024+5120s+9216): overlays guard/F_{<=s}, which are
//     consumed before the H_s writes (wave-private, in-order DS + barriers)
#define WAVE_SZ 25600
#define SMEM_BYTES (7424 + 2 * WAVE_SZ)

// One thread per POINT: union-fetch the (2+sx)(2+sy) <= 9 table entries per
// level shared by the point's 4 plane corners (vs 16 redundant gathers),
// then 4 static-select bilerps. MLP (MFMA) runs 4 sub-rounds of 64
// corner-rows per wave. NO dynamic register-array indexing anywhere.
template <int TBF>
__global__ __launch_bounds__(128) void plane_fwd(
    const F2* __restrict__ xy,
    const F2* __restrict__ table,
    const unsigned* __restrict__ tbf16,
    const float* __restrict__ w0g,
    const float* __restrict__ w1g,
    const int* __restrict__ boundp,
    float* __restrict__ out,
    EncParams P)
{
  __shared__ __align__(16) char smem[SMEM_BYTES];
  const int t = threadIdx.x;
  const int w = t >> 6;
  const int L = t & 63;
  const int r16 = L & 15, g = L >> 4;

  // ---- stage W0 (bf16 [64][32] stride 80) ----
  {
    const float4* s4 = (const float4*)w0g;  // 512 float4
    #pragma unroll
    for (int it = 0; it < 4; ++it) {
      int f = t + it * 128;
      float4 a = s4[f];
      *(uint2*)(smem + (f >> 3) * 80 + (f & 7) * 8) =
          make_uint2(bf2pack(a.x, a.y), bf2pack(a.z, a.w));
    }
  }
  // ---- stage W1 (bf16 [16][64] stride 144; rows 8..15 zero) ----
  {
    const float4* s4 = (const float4*)w1g;  // 128 float4
    float4 a = s4[t];
    *(uint2*)(smem + 5120 + (t >> 4) * 144 + (t & 15) * 8) =
        make_uint2(bf2pack(a.x, a.y), bf2pack(a.z, a.w));
    for (int i = t; i < 144; i += 128)
      *(uint2*)(smem + 5120 + 1152 + i * 8) = make_uint2(0u, 0u);
  }

  char* wbase = smem + 7424 + w * WAVE_SZ;
  char* Fbase = wbase + 5120;

  // ---- per-point setup ----
  const int p = blockIdx.x * 128 + t;
  F2 pxy = xy[p];

  int braw = boundp[0];
  float bf = (braw > 0x00800000) ? __int_as_float(braw) : (float)braw;
  float inv2b = 0.5f / bf;
  float xn = (pxy.x + bf) * inv2b;
  float yn = (pxy.y + bf) * inv2b;

  float cx  = fminf(fmaxf(xn * 2048.0f - 0.5f, 0.0f), 2047.0f);
  float cyv = fminf(fmaxf(yn * 2048.0f - 0.5f, 0.0f), 2047.0f);
  float cx0 = floorf(cx), cy0 = floorf(cyv);
  float u = cx - cx0, v = cyv - cy0;
  float cx1 = fminf(cx0 + 1.0f, 2047.0f);
  float cy1 = fminf(cy0 + 1.0f, 2047.0f);

  const float K = 1.0f / 2048.0f;
  const float gx0 = (cx0 + 0.5f) * K, gx1 = (cx1 + 0.5f) * K;
  const float gy0 = (cy0 + 0.5f) * K, gy1 = (cy1 + 0.5f) * K;

  // corner weights, c = {A:(x0,y0), B:(x1,y0), C:(x0,y1), D:(x1,y1)}
  {
    f32x4 wcv;
    wcv.x = (1.0f - u) * (1.0f - v);
    wcv.y = u * (1.0f - v);
    wcv.z = (1.0f - u) * v;
    wcv.w = u * v;
    *(f32x4*)(wbase + L * 16) = wcv;
  }

  unsigned fwA[16], fwB[16], fwC[16], fwD[16];

  #pragma unroll
  for (int l = 0; l < 16; ++l) {
    const float scale   = P.lv[l].scale;
    const unsigned res  = P.lv[l].res;
    const unsigned size = P.lv[l].size;
    const unsigned off  = P.lv[l].offset;
    const bool hashed = (res * res) > size;  // wave-uniform

    float pxa = fmaf(gx0, scale, 0.5f); float fa = floorf(pxa);
    float frx0 = pxa - fa; unsigned ux0 = (unsigned)fa;
    float pxb = fmaf(gx1, scale, 0.5f); float fb = floorf(pxb);
    float frx1 = pxb - fb; unsigned ux1 = (unsigned)fb;
    float pya = fmaf(gy0, scale, 0.5f); float fc = floorf(pya);
    float fry0 = pya - fc; unsigned uy0 = (unsigned)fc;
    float pyb = fmaf(gy1, scale, 0.5f); float fd = floorf(pyb);
    float fry1 = pyb - fd; unsigned uy1 = (unsigned)fd;

    const unsigned sx = ux1 - ux0;   // 0 or 1 (corner sep = scale/2048 < 1)
    const unsigned sy = uy1 - uy0;

    // union cell indices k[j][i], j=y in {0..1+sy}, i=x in {0..1+sx}
    unsigned k00, k01, k02, k10, k11, k12, k20, k21, k22;
    if (hashed) {
      const unsigned m = size - 1u;  // size == 2^19
      unsigned hy0 = uy0 * PRIME_Y, hy1 = hy0 + PRIME_Y, hy2 = hy1 + PRIME_Y;
      k00 = (ux0 ^ hy0) & m; k01 = ((ux0 + 1u) ^ hy0) & m; k02 = ((ux0 + 2u) ^ hy0) & m;
      k10 = (ux0 ^ hy1) & m; k11 = ((ux0 + 1u) ^ hy1) & m; k12 = ((ux0 + 2u) ^ hy1) & m;
      k20 = (ux0 ^ hy2) & m; k21 = ((ux0 + 1u) ^ hy2) & m; k22 = ((ux0 + 2u) ^ hy2) & m;
    } else {
      // row-major linear index mod size, identical arithmetic to reference
      unsigned r0 = ux0 + uy0 * res;
      unsigned r1 = r0 + res; r1 = r1 >= size ? r1 - size : r1;
      unsigned r2 = r1 + res; r2 = r2 >= size ? r2 - size : r2;
      k00 = r0;       k01 = r0 + 1u;  k02 = r0 + 2u;
      k10 = r1;       k11 = r1 + 1u;  k12 = r1 + 2u;
      k20 = r2;       k21 = r2 + 1u;  k22 = r2 + 2u;
      k01 = k01 >= size ? k01 - size : k01;
      k02 = k02 >= size ? k02 - size : k02;
      k11 = k11 >= size ? k11 - size : k11;
      k12 = k12 >= size ? k12 - size : k12;
      k21 = k21 >= size ? k21 - size : k21;
      k22 = k22 >= size ? k22 - size : k22;
    }

    // predicated union loads (packed bf16, 4 B each)
    unsigned e00 = 0, e01 = 0, e02 = 0, e10 = 0, e11 = 0, e12 = 0,
             e20 = 0, e21 = 0, e22 = 0;
    if (TBF) {
      const unsigned* tb = tbf16 + off;
      e00 = tb[k00]; e01 = tb[k01];
      e10 = tb[k10]; e11 = tb[k11];
      if (sx) { e02 = tb[k02]; e12 = tb[k12]; }
      if (sy) {
        e20 = tb[k20]; e21 = tb[k21];
        if (sx) e22 = tb[k22];
      }
    } else {
      const F2* tb = table + off;
      F2 a0 = tb[k00], a1 = tb[k01], b0 = tb[k10], b1 = tb[k11];
      e00 = bf2pack(a0.x, a0.y); e01 = bf2pack(a1.x, a1.y);
      e10 = bf2pack(b0.x, b0.y); e11 = bf2pack(b1.x, b1.y);
      if (sx) { F2 q = tb[k02], r = tb[k12];
                e02 = bf2pack(q.x, q.y); e12 = bf2pack(r.x, r.y); }
      if (sy) { F2 q = tb[k20], r = tb[k21];
                e20 = bf2pack(q.x, q.y); e21 = bf2pack(r.x, r.y);
                if (sx) { F2 s2 = tb[k22]; e22 = bf2pack(s2.x, s2.y); } }
    }

    // y-side-1 rows = rows (sy, sy+1)  -- static cndmask selects only
    unsigned ya0 = sy ? e10 : e00, ya1 = sy ? e11 : e01, ya2 = sy ? e12 : e02;
    unsigned yb0 = sy ? e20 : e10, yb1 = sy ? e21 : e11, yb2 = sy ? e22 : e12;

    // corner A (x0,y0)
    v2f fA = bilerp(e00, e01, e10, e11, frx0, fry0);
    // corner B (x1,y0): cols (sx, sx+1)
    unsigned b00 = sx ? e01 : e00, b10 = sx ? e02 : e01;
    unsigned b01 = sx ? e11 : e10, b11 = sx ? e12 : e11;
    v2f fB = bilerp(b00, b10, b01, b11, frx1, fry0);
    // corner C (x0,y1)
    v2f fC = bilerp(ya0, ya1, yb0, yb1, frx0, fry1);
    // corner D (x1,y1)
    unsigned d00 = sx ? ya1 : ya0, d10 = sx ? ya2 : ya1;
    unsigned d01 = sx ? yb1 : yb0, d11 = sx ? yb2 : yb1;
    v2f fD = bilerp(d00, d10, d01, d11, frx1, fry1);

    fwA[l] = bf2pack(fA.x, fA.y);
    fwB[l] = bf2pack(fB.x, fB.y);
    fwC[l] = bf2pack(fC.x, fC.y);
    fwD[l] = bf2pack(fD.x, fD.y);
  }

  // ---- write 4 corner-feature rows: chunk (L>>4), row = c*16 + (L&15) ----
  {
    char* fr = Fbase + (L >> 4) * 5120 + (L & 15) * 80;
    *(uint4*)(fr +  0) = make_uint4(fwA[0],  fwA[1],  fwA[2],  fwA[3]);
    *(uint4*)(fr + 16) = make_uint4(fwA[4],  fwA[5],  fwA[6],  fwA[7]);
    *(uint4*)(fr + 32) = make_uint4(fwA[8],  fwA[9],  fwA[10], fwA[11]);
    *(uint4*)(fr + 48) = make_uint4(fwA[12], fwA[13], fwA[14], fwA[15]);
    fr += 1280;
    *(uint4*)(fr +  0) = make_uint4(fwB[0],  fwB[1],  fwB[2],  fwB[3]);
    *(uint4*)(fr + 16) = make_uint4(fwB[4],  fwB[5],  fwB[6],  fwB[7]);
    *(uint4*)(fr + 32) = make_uint4(fwB[8],  fwB[9],  fwB[10], fwB[11]);
    *(uint4*)(fr + 48) = make_uint4(fwB[12], fwB[13], fwB[14], fwB[15]);
    fr += 1280;
    *(uint4*)(fr +  0) = make_uint4(fwC[0],  fwC[1],  fwC[2],  fwC[3]);
    *(uint4*)(fr + 16) = make_uint4(fwC[4],  fwC[5],  fwC[6],  fwC[7]);
    *(uint4*)(fr + 32) = make_uint4(fwC[8],  fwC[9],  fwC[10], fwC[11]);
    *(uint4*)(fr + 48) = make_uint4(fwC[12], fwC[13], fwC[14], fwC[15]);
    fr += 1280;
    *(uint4*)(fr +  0) = make_uint4(fwD[0],  fwD[1],  fwD[2],  fwD[3]);
    *(uint4*)(fr + 16) = make_uint4(fwD[4],  fwD[5],  fwD[6],  fwD[7]);
    *(uint4*)(fr + 32) = make_uint4(fwD[8],  fwD[9],  fwD[10], fwD[11]);
    *(uint4*)(fr + 48) = make_uint4(fwD[12], fwD[13], fwD[14], fwD[15]);
  }

  __syncthreads();

  // ---- MLP: W0/W1 A-fragments held in regs across sub-rounds ----
  short8 afr[4];
  #pragma unroll
  for (int a = 0; a < 4; ++a)
    afr[a] = *(const short8*)(smem + (16 * a + r16) * 80 + g * 16);
  short8 a2f[2];
  #pragma unroll
  for (int ks = 0; ks < 2; ++ks)
    a2f[ks] = *(const short8*)(smem + 5120 + r16 * 144 + ks * 64 + g * 16);

  #pragma unroll
  for (int s = 0; s < 4; ++s) {
    char* Fs = Fbase + s * 5120;
    char* Hs = wbase + 1024 + s * 5120;

    short8 bfr[4];
    #pragma unroll
    for (int b = 0; b < 4; ++b)
      bfr[b] = *(const short8*)(
          Fs + ((r16 & 3) * 16 + 4 * b + (r16 >> 2)) * 80 + g * 16);

    f32x4 acc[4][4];
    #pragma unroll
    for (int a = 0; a < 4; ++a)
      #pragma unroll
      for (int b = 0; b < 4; ++b)
        acc[a][b] = (f32x4){0.f, 0.f, 0.f, 0.f};

    #pragma unroll
    for (int a = 0; a < 4; ++a)
      #pragma unroll
      for (int b = 0; b < 4; ++b)
        acc[a][b] = __builtin_amdgcn_mfma_f32_16x16x32_bf16(
            afr[a], bfr[b], acc[a][b], 0, 0, 0);

    // relu + pack, H[m][j] stride 144 (j = 16a + 4g + reg)
    #pragma unroll
    for (int a = 0; a < 4; ++a)
      #pragma unroll
      for (int b = 0; b < 4; ++b) {
        f32x4 h = acc[a][b];
        float h0 = fmaxf(h.x, 0.f), h1 = fmaxf(h.y, 0.f);
        float h2 = fmaxf(h.z, 0.f), h3 = fmaxf(h.w, 0.f);
        *(uint2*)(Hs + (16 * b + r16) * 144 + a * 32 + g * 8) =
            make_uint2(bf2pack(h0, h1), bf2pack(h2, h3));
      }

    __syncthreads();

    f32x4 oacc[4];
    #pragma unroll
    for (int b = 0; b < 4; ++b) oacc[b] = (f32x4){0.f, 0.f, 0.f, 0.f};

    #pragma unroll
    for (int ks = 0; ks < 2; ++ks) {
      #pragma unroll
      for (int b = 0; b < 4; ++b) {
        short8 b2 = *(const short8*)(Hs + (16 * b + r16) * 144 + ks * 64 + g * 16);
        oacc[b] = __builtin_amdgcn_mfma_f32_16x16x32_bf16(a2f[ks], b2, oacc[b], 0, 0, 0);
      }
    }

    // blend corners (wc from LDS) + quad reduce + store
    #pragma unroll
    for (int b = 0; b < 4; ++b) {
      float wcm = *(const float*)(
          wbase + (16 * s + 4 * b + (r16 >> 2)) * 16 + (r16 & 3) * 4);
      float v0 = oacc[b].x * wcm;
      float v1 = oacc[b].y * wcm;
      float v2 = oacc[b].z * wcm;
      float v3 = oacc[b].w * wcm;
      v0 += __shfl_xor(v0, 1, 64); v0 += __shfl_xor(v0, 2, 64);
      v1 += __shfl_xor(v1, 1, 64); v1 += __shfl_xor(v1, 2, 64);
      v2 += __shfl_xor(v2, 1, 64); v2 += __shfl_xor(v2, 2, 64);
      v3 += __shfl_xor(v3, 1, 64); v3 += __shfl_xor(v3, 2, 64);
      if ((L & 3) == 0 && g < 2) {
        int pt = blockIdx.x * 128 + w * 64 + 16 * s + 4 * b + (r16 >> 2);
        *(f32x4*)(out + (size_t)pt * 8 + 4 * g) = (f32x4){v0, v1, v2, v3};
      }
    }
  }
}

extern "C" void kernel_launch(void* const* d_in, const int* in_sizes, int n_in,
                              void* d_out, int out_size, void* d_ws, size_t ws_size,
                              hipStream_t stream) {
  EncParams P;
  double b = exp2(log2(2048.0 / 16.0) / 15.0);
  unsigned off = 0;
  for (int l = 0; l < 16; ++l) {
    double s = 16.0 * pow(b, (double)l) - 1.0;
    int r = (int)ceil(s) + 1;
    unsigned p = (unsigned)(r * r);
    if (p > 524288u) p = 524288u;        // min(HASHMAP_MAX, r*r)
    p = (p + 7u) / 8u * 8u;              // align to 8 entries
    P.lv[l].scale = (float)s;
    P.lv[l].res = (unsigned)r;
    P.lv[l].size = p;
    P.lv[l].offset = off;
    off += p;
  }
  const int total_params = (int)off;

  const int N = in_sizes[0] / 2;  // xy is [N,2]
  const F2* xy = (const F2*)d_in[0];
  const F2* table = (const F2*)d_in[1];
  const float* w0g = (const float*)d_in[2];
  const float* w1g = (const float*)d_in[3];
  const int* bp = (const int*)d_in[4];
  float* outp = (float*)d_out;

  if (ws_size >= (size_t)total_params * 4) {
    unsigned* tbf = (unsigned*)d_ws;
    cvt_table<<<(total_params + 255) / 256, 256, 0, stream>>>(table, tbf,
                                                             total_params);
    plane_fwd<1><<<N / 128, 128, 0, stream>>>(xy, table, tbf, w0g, w1g, bp,
                                              outp, P);
  } else {
    plane_fwd<0><<<N / 128, 128, 0, stream>>>(xy, table, nullptr, w0g, w1g, bp,
                                              outp, P);
  }
}